// Round 1
// baseline (202.910 us; speedup 1.0000x reference)
//
#include <hip/hip_runtime.h>
#include <math.h>

#define N_PTS 2048
#define BLOCK 256

// One block handles: one (b,s) pair, one chunk of 256 query points, one direction.
// dir=0: query=pred, candidates=target (p2t).  dir=1: swapped (t2p).
// Inner loop per pair: v = |q|^2 - 2*p.q ; best = min(best, v).
// Final distance = sqrt(max(|p|^2 + best, 0)) — identical identity to the JAX ref.
__global__ __launch_bounds__(BLOCK) void chamfer_kernel(
    const float* __restrict__ pred,
    const float* __restrict__ tgt,
    float* __restrict__ out)
{
    __shared__ float4 q[N_PTS];        // (x, y, z, |q|^2) — 32 KB
    __shared__ float red[BLOCK / 64];

    const int bs    = blockIdx.x;      // 0..31  (b*8 + s)
    const int chunk = blockIdx.y;      // 0..7
    const int dir   = blockIdx.z;      // 0..1

    const float* Abase = (dir ? tgt : pred) + (size_t)bs * N_PTS * 3;
    const float* Bbase = (dir ? pred : tgt) + (size_t)bs * N_PTS * 3;
    const int tid = threadIdx.x;

    // Stage candidate cloud into LDS with |q|^2 precomputed.
    for (int i = tid; i < N_PTS; i += BLOCK) {
        float x = Bbase[3 * i + 0];
        float y = Bbase[3 * i + 1];
        float z = Bbase[3 * i + 2];
        q[i] = make_float4(x, y, z, x * x + y * y + z * z);
    }
    __syncthreads();

    // Each thread owns one query point.
    const int p = chunk * BLOCK + tid;
    const float px = Abase[3 * p + 0];
    const float py = Abase[3 * p + 1];
    const float pz = Abase[3 * p + 2];
    const float p2 = px * px + py * py + pz * pz;

    float best = 3.4e38f;
    #pragma unroll 8
    for (int j = 0; j < N_PTS; ++j) {
        float4 t = q[j];                             // broadcast ds_read_b128
        float dot = px * t.x + py * t.y + pz * t.z;  // mul + 2 fma
        float v = fmaf(-2.0f, dot, t.w);             // |q|^2 - 2 p.q
        best = fminf(best, v);
    }

    float d = sqrtf(fmaxf(p2 + best, 0.0f));

    // Wave (64-lane) shuffle reduction, then cross-wave via LDS.
    for (int off = 32; off > 0; off >>= 1)
        d += __shfl_down(d, off, 64);
    if ((tid & 63) == 0) red[tid >> 6] = d;
    __syncthreads();
    if (tid == 0) {
        float s = red[0] + red[1] + red[2] + red[3];
        // scale: 1/(B*S*N) == 1/(B*S*M) == 1/65536
        atomicAdd(out, s * (1.0f / 65536.0f));
    }
}

extern "C" void kernel_launch(void* const* d_in, const int* in_sizes, int n_in,
                              void* d_out, int out_size, void* d_ws, size_t ws_size,
                              hipStream_t stream) {
    const float* pred = (const float*)d_in[0];
    const float* tgt  = (const float*)d_in[1];
    float* out = (float*)d_out;

    hipMemsetAsync(out, 0, sizeof(float), stream);

    dim3 grid(32, 8, 2);
    chamfer_kernel<<<grid, BLOCK, 0, stream>>>(pred, tgt, out);
}

// Round 2
// 81.863 us; speedup vs baseline: 2.4786x; 2.4786x over previous
//
#include <hip/hip_runtime.h>
#include <math.h>

#define N_PTS   2048
#define BLOCK   256
#define NQ      8      // queries per thread -> 2048 queries per block (whole cloud)
#define SLAB    128    // candidates staged per block
#define NSLAB   (N_PTS / SLAB)   // 16

// Grid: (32 bs, 2 dir, 16 slab) = 1024 blocks, 256 threads.
// Each block: stage 128 candidates as (x,y,z,|q|^2) in LDS, each thread tracks
// running min of (|q|^2 - 2 p.q) for its 8 query points (3 FMA + 1 min per pair),
// then clamps d^2 >= 0 and atomicMin's the uint bit pattern into ws.
// (uint ordering == float ordering for non-negative floats.)
__global__ __launch_bounds__(BLOCK) void chamfer_min_kernel(
    const float* __restrict__ pred,
    const float* __restrict__ tgt,
    unsigned int* __restrict__ wsmin)
{
    __shared__ float4 sh[SLAB];

    const int bs   = blockIdx.x;   // 0..31
    const int dir  = blockIdx.y;   // 0..1
    const int slab = blockIdx.z;   // 0..15
    const int tid  = threadIdx.x;

    const float* Abase = (dir ? tgt : pred) + (size_t)bs * N_PTS * 3;  // queries
    const float* Bbase = (dir ? pred : tgt) + (size_t)bs * N_PTS * 3;  // candidates

    // Stage this slab of candidates with |q|^2 precomputed.
    if (tid < SLAB) {
        const int j = slab * SLAB + tid;
        const float x = Bbase[3 * j + 0];
        const float y = Bbase[3 * j + 1];
        const float z = Bbase[3 * j + 2];
        sh[tid] = make_float4(x, y, z, x * x + y * y + z * z);
    }
    __syncthreads();

    // Load 8 query points; pre-scale by -2 so the pair op is pure FMA.
    float nx[NQ], ny[NQ], nz[NQ], p2[NQ], best[NQ];
    #pragma unroll
    for (int k = 0; k < NQ; ++k) {
        const int q = tid + BLOCK * k;
        const float px = Abase[3 * q + 0];
        const float py = Abase[3 * q + 1];
        const float pz = Abase[3 * q + 2];
        nx[k] = -2.0f * px;
        ny[k] = -2.0f * py;
        nz[k] = -2.0f * pz;
        p2[k] = px * px + py * py + pz * pz;
        best[k] = 3.4e38f;
    }

    // Hot loop: 1 ds_read_b128 feeds 8 queries x (3 FMA + 1 min).
    #pragma unroll 2
    for (int j = 0; j < SLAB; ++j) {
        const float4 t = sh[j];
        #pragma unroll
        for (int k = 0; k < NQ; ++k) {
            const float v = fmaf(nx[k], t.x,
                            fmaf(ny[k], t.y,
                            fmaf(nz[k], t.z, t.w)));   // |q|^2 - 2 p.q
            best[k] = fminf(best[k], v);
        }
    }

    // Combine partial mins across slabs via uint atomicMin (d2 clamped >= 0).
    const int base = (dir * 32 + bs) * N_PTS;
    #pragma unroll
    for (int k = 0; k < NQ; ++k) {
        const float d2 = fmaxf(p2[k] + best[k], 0.0f);
        atomicMin(&wsmin[base + tid + BLOCK * k], __float_as_uint(d2));
    }
}

// 131072 min-d^2 values -> sqrt -> sum / 65536 -> out scalar.
// Grid: 128 blocks x 256 threads, exactly one float4 per thread.
__global__ __launch_bounds__(BLOCK) void chamfer_finalize_kernel(
    const float4* __restrict__ wsmin,
    float* __restrict__ out)
{
    __shared__ float red[BLOCK / 64];
    const int i = blockIdx.x * BLOCK + threadIdx.x;
    const float4 t = wsmin[i];
    float s = sqrtf(t.x) + sqrtf(t.y) + sqrtf(t.z) + sqrtf(t.w);

    for (int off = 32; off > 0; off >>= 1)
        s += __shfl_down(s, off, 64);
    const int tid = threadIdx.x;
    if ((tid & 63) == 0) red[tid >> 6] = s;
    __syncthreads();
    if (tid == 0) {
        const float blk = red[0] + red[1] + red[2] + red[3];
        atomicAdd(out, blk * (1.0f / 65536.0f));  // 1/(B*S*N), N==M
    }
}

extern "C" void kernel_launch(void* const* d_in, const int* in_sizes, int n_in,
                              void* d_out, int out_size, void* d_ws, size_t ws_size,
                              hipStream_t stream) {
    const float* pred = (const float*)d_in[0];
    const float* tgt  = (const float*)d_in[1];
    float* out = (float*)d_out;
    unsigned int* wsmin = (unsigned int*)d_ws;   // 2*32*2048 = 131072 uints (512 KB)

    // Init: ws to +large (0x7F7F7F7F = 3.39e38f, uint-order-consistent), out to 0.
    hipMemsetAsync(wsmin, 0x7F, (size_t)131072 * sizeof(unsigned int), stream);
    hipMemsetAsync(out, 0, sizeof(float), stream);

    dim3 grid(32, 2, NSLAB);
    chamfer_min_kernel<<<grid, BLOCK, 0, stream>>>(pred, tgt, wsmin);

    chamfer_finalize_kernel<<<131072 / (BLOCK * 4), BLOCK, 0, stream>>>(
        (const float4*)wsmin, out);
}